// Round 10
// baseline (57.163 us; speedup 1.0000x reference)
//
#include <hip/hip_runtime.h>
#include <hip/hip_bf16.h>
#include <math.h>

// Problem sizes
#define Bn 4096
#define Dn 128
#define Cn 1000
#define Qn 65536
#define CPAD 1024   // proto rows padded (zeros) so fragment loads are in-bounds

typedef __attribute__((ext_vector_type(8))) short short8v;  // bf16x8 MFMA frag
typedef __attribute__((ext_vector_type(4))) short short4v;  // bf16x4 store
typedef __attribute__((ext_vector_type(4))) float f32x4;    // fp32x4 acc frag
typedef __attribute__((ext_vector_type(4))) float f4v;      // native float4

__device__ inline float waveAllMaxF(float v) {
    for (int o = 32; o; o >>= 1) v = fmaxf(v, __shfl_xor(v, o));
    return v;
}
__device__ inline float waveAllSumF(float v) {
    for (int o = 32; o; o >>= 1) v += __shfl_xor(v, o);
    return v;
}
__device__ inline float waveSumF(float v) {
    for (int o = 32; o; o >>= 1) v += __shfl_down(v, o);
    return v;
}
__device__ inline short f2bf(float x) {
    union { __hip_bfloat16 h; short s; } u;
    u.h = __float2bfloat16(x);
    return u.s;
}

// ================= PHASE 1 =================
// 3072 blocks in 1024 groups of 3: 1 cls + 2 copy.  (identical to round 9)
__global__ __launch_bounds__(256) void k_phase1(
    const float* __restrict__ logits, const float* __restrict__ plabel,
    const float* __restrict__ q, const float* __restrict__ proto,
    const float* __restrict__ kk, const float* __restrict__ queue,
    const int* __restrict__ ptrp,
    float* __restrict__ out_cls, int* __restrict__ labels,
    __hip_bfloat16* __restrict__ qb, __hip_bfloat16* __restrict__ pb,
    float* __restrict__ out_feat, float* __restrict__ out_queue)
{
    int bid = blockIdx.x, t = threadIdx.x;
    int g = bid / 3, s = bid % 3;

    if (s != 0) {
        // ---- copy block (2048 total) ----
        int cidx = g * 2 + (s - 1);
        int p = *ptrp;
        int pc = p < 0 ? 0 : (p > Qn - Bn ? Qn - Bn : p);   // dynamic_update_slice clamp
        const long long QD = (long long)Bn * Dn;                  // 524288
        const long long n4 = (2 * QD + (long long)Qn * Dn) / 4;   // 2359296
        const long long stride = 2048LL * 256;
        for (long long i = (long long)cidx * 256 + t; i < n4; i += stride) {
            long long off = i * 4;
            if (off < QD) {
                *(f4v*)(out_feat + off) = *(const f4v*)(q + off);
            } else if (off < 2 * QD) {
                *(f4v*)(out_feat + off) = *(const f4v*)(kk + off - QD);
            } else {
                long long qoff = off - 2 * QD;
                f4v v = *(const f4v*)(queue + qoff);
                *(f4v*)(out_feat + off) = v;
                int row = (int)(qoff >> 7);
                int col = (int)(qoff & 127);
                unsigned rr = (unsigned)(row - pc);
                if (rr < (unsigned)Bn) v = *(const f4v*)(kk + (long long)rr * Dn + col);
                *(f4v*)(out_queue + qoff) = v;
            }
        }
        return;
    }

    // ---- cls block (1024 total): 4 rows, one wave per row ----
    if (t < 160) {
        int idx4 = g * 160 + t;
        if (idx4 < 131072) {                      // q: 524288/4
            f4v v = *(const f4v*)(q + (long long)idx4 * 4);
            short4v o = {f2bf(v.x), f2bf(v.y), f2bf(v.z), f2bf(v.w)};
            *(short4v*)((short*)qb + (long long)idx4 * 4) = o;
        } else {
            int j4 = idx4 - 131072;               // proto: 32768 float4 slots (padded)
            short4v o = {0, 0, 0, 0};
            if (j4 < 32000) {
                f4v v = *(const f4v*)(proto + (long long)j4 * 4);
                o = (short4v){f2bf(v.x), f2bf(v.y), f2bf(v.z), f2bf(v.w)};
            }
            *(short4v*)((short*)pb + (long long)j4 * 4) = o;
        }
    }

    int lane = t & 63, wid = t >> 6;
    int row = g * 4 + wid;
    const float* x = logits + (long long)row * Cn;

    float vv[16];
    float mx = -INFINITY;
#pragma unroll
    for (int j = 0; j < 4; ++j) {
        int f4i = lane + j * 64;
        f4v v = (f4v){-INFINITY, -INFINITY, -INFINITY, -INFINITY};
        if (f4i < 250) v = *(const f4v*)(x + f4i * 4);
        vv[j * 4 + 0] = v.x; vv[j * 4 + 1] = v.y;
        vv[j * 4 + 2] = v.z; vv[j * 4 + 3] = v.w;
        mx = fmaxf(mx, fmaxf(fmaxf(v.x, v.y), fmaxf(v.z, v.w)));
    }
    mx = waveAllMaxF(mx);

    float ssum = 0.f;
#pragma unroll
    for (int u = 0; u < 16; ++u) {
        vv[u] = expf(vv[u] - mx);      // exp(-inf - mx) = 0 for masked slots
        ssum += vv[u];
    }
    ssum = waveAllSumF(ssum);
    float inv = 1.f / ssum;

    float bv = -INFINITY; int bi = Cn;
#pragma unroll
    for (int j = 0; j < 4; ++j) {
        int f4i = lane + j * 64;
        if (f4i < 250) {
            float o0 = vv[j * 4 + 0] * inv, o1 = vv[j * 4 + 1] * inv;
            float o2 = vv[j * 4 + 2] * inv, o3 = vv[j * 4 + 3] * inv;
            *((f4v*)(out_cls + (long long)row * Cn) + f4i) = (f4v){o0, o1, o2, o3};
            f4v p4 = *((const f4v*)(plabel + (long long)row * Cn) + f4i);
            float pr[4] = {o0 * p4.x, o1 * p4.y, o2 * p4.z, o3 * p4.w};
#pragma unroll
            for (int jj = 0; jj < 4; ++jj) {
                if (pr[jj] > bv) { bv = pr[jj]; bi = f4i * 4 + jj; }
            }
        }
    }
    for (int o = 32; o; o >>= 1) {
        float ov = __shfl_xor(bv, o);
        int   oi = __shfl_xor(bi, o);
        if (ov > bv || (ov == bv && oi < bi)) { bv = ov; bi = oi; }
    }
    if (lane == 0) labels[row] = bi;
}

// ================= PHASE 2 =================
// 1301 blocks:
//   bid <  256 : cluster GEMM + row softmax (16 rows/block)
//   bid <  756 : prototype closed-form update + L2 norm (2 classes/block)
//   else       : cont_labels / new_queue_pseudo / new_ptr tail (545 blocks)
__global__ __launch_bounds__(256) void k_phase2(
    const __hip_bfloat16* __restrict__ qb, const __hip_bfloat16* __restrict__ pb,
    const float* __restrict__ proto, const float* __restrict__ q,
    const int* __restrict__ lbl, const float* __restrict__ qps,
    const int* __restrict__ ptrp,
    float* __restrict__ outC, float* __restrict__ outp,
    float* __restrict__ out_lab, float* __restrict__ out_qps,
    float* __restrict__ out_ptr)
{
    __shared__ __align__(16) char smem[16448];
    int bid = blockIdx.x, t = threadIdx.x;

    if (bid < 256) {
        // ---- GEMM + softmax ----
        float (*red)[4] = (float (*)[4])smem;   // [16][4]
        int lane = t & 63, w = t >> 6;
        int la = lane & 15, lk = lane >> 4;
        int row0 = bid * 16;

        f32x4 acc[16];
#pragma unroll
        for (int j = 0; j < 16; ++j) acc[j] = (f32x4){0.f, 0.f, 0.f, 0.f};

        const short* A = (const short*)qb + (long long)(row0 + la) * Dn;
        const short* Bp = (const short*)pb;
#pragma unroll
        for (int kc = 0; kc < Dn; kc += 32) {
            short8v a = *(const short8v*)(A + kc + lk * 8);
#pragma unroll
            for (int j = 0; j < 16; ++j) {
                int prow = w * 256 + j * 16 + la;
                short8v b = *(const short8v*)(Bp + (long long)prow * Dn + kc + lk * 8);
                acc[j] = __builtin_amdgcn_mfma_f32_16x16x32_bf16(a, b, acc[j], 0, 0, 0);
            }
        }

        float m[4];
#pragma unroll
        for (int rg = 0; rg < 4; ++rg) {
            float v = -INFINITY;
#pragma unroll
            for (int j = 0; j < 16; ++j) {
                int col = w * 256 + j * 16 + la;
                if (col < Cn) v = fmaxf(v, acc[j][rg]);
            }
#pragma unroll
            for (int o = 1; o < 16; o <<= 1) v = fmaxf(v, __shfl_xor(v, o));
            m[rg] = v;
        }
        if (la == 0) {
#pragma unroll
            for (int rg = 0; rg < 4; ++rg) red[lk * 4 + rg][w] = m[rg];
        }
        __syncthreads();
#pragma unroll
        for (int rg = 0; rg < 4; ++rg) {
            int r = lk * 4 + rg;
            m[rg] = fmaxf(fmaxf(red[r][0], red[r][1]), fmaxf(red[r][2], red[r][3]));
        }
        __syncthreads();

        float s[4];
#pragma unroll
        for (int rg = 0; rg < 4; ++rg) {
            float v = 0.f;
#pragma unroll
            for (int j = 0; j < 16; ++j) {
                int col = w * 256 + j * 16 + la;
                float e = (col < Cn) ? expf(acc[j][rg] - m[rg]) : 0.f;
                acc[j][rg] = e;
                v += e;
            }
#pragma unroll
            for (int o = 1; o < 16; o <<= 1) v += __shfl_xor(v, o);
            s[rg] = v;
        }
        if (la == 0) {
#pragma unroll
            for (int rg = 0; rg < 4; ++rg) red[lk * 4 + rg][w] = s[rg];
        }
        __syncthreads();
#pragma unroll
        for (int rg = 0; rg < 4; ++rg) {
            int r = lk * 4 + rg;
            s[rg] = 1.f / (red[r][0] + red[r][1] + red[r][2] + red[r][3]);
        }

#pragma unroll
        for (int j = 0; j < 16; ++j) {
            int col = w * 256 + j * 16 + la;
            if (col < Cn) {
                int rowb = row0 + lk * 4;
#pragma unroll
                for (int rg = 0; rg < 4; ++rg)
                    outC[(long long)(rowb + rg) * Cn + col] = acc[j][rg] * s[rg];
            }
        }
    } else if (bid < 756) {
        // ---- prototype closed-form update + L2 norm, 2 classes/block ----
        // Wave (h,hw) ballot-scans labels[hw*2048, +2048) for class c(h) directly
        // from global (L2-resident), building an ORDERED match list in its own
        // LDS region. Then closed form: v = proto*0.99^n + sum 0.01*0.99^(n-1-mi)*q.
        unsigned short* lst = (unsigned short*)smem;          // [2][2][2048]
        int*   nm2 = (int*)(smem + 16384);                    // [4]
        float* shh = (float*)(smem + 16400);                  // [4]

        int h = t >> 7, tt = t & 127;
        int ln = t & 63, hw = (t >> 6) & 1;
        int c = (bid - 256) * 2 + h;                          // < 1000 always
        unsigned short* myl = lst + (h * 2 + hw) * 2048;

        int base = hw * 2048;
        int n = 0;
        for (int jj = 0; jj < 32; ++jj) {
            int lj = lbl[base + jj * 64 + ln];
            unsigned long long mask = __ballot(lj == c);
            if (ln == 0) {
                while (mask) {
                    int b = __builtin_ctzll(mask);
                    myl[n++] = (unsigned short)(base + jj * 64 + b);
                    mask &= mask - 1;
                }
            }
        }
        if (ln == 0) nm2[h * 2 + hw] = n;
        __syncthreads();

        int n0 = nm2[h * 2 + 0];
        int n1 = nm2[h * 2 + 1];
        int nn = n0 + n1;
        const unsigned short* l0 = lst + (h * 2 + 0) * 2048;
        const unsigned short* l1 = lst + (h * 2 + 1) * 2048;

        float acc = 0.f;
#pragma unroll 4
        for (int mi = 0; mi < nn; ++mi) {
            int r = (mi < n0) ? l0[mi] : l1[mi - n0];
            float wv = 0.01f * __powf(0.99f, (float)(nn - 1 - mi));
            acc += wv * q[(long long)r * Dn + tt];
        }
        float decay = __powf(0.99f, (float)nn);
        float v = proto[(long long)c * Dn + tt] * decay + acc;

        float ss = waveSumF(v * v);
        if (ln == 0) shh[t >> 6] = ss;
        __syncthreads();
        float nrm = sqrtf(shh[h * 2] + shh[h * 2 + 1]);
        outp[(long long)c * Dn + tt] = v / fmaxf(nrm, 1e-12f);
    } else {
        // ---- labels / queue_pseudo / ptr tail ----
        int gid = (bid - 756) * 256 + t;
        const int NL = 2 * Bn + Qn;   // 73728
        int p = *ptrp;
        int pc = p < 0 ? 0 : (p > Qn - Bn ? Qn - Bn : p);
        if (gid < NL) {
            float v;
            if (gid < Bn)          v = (float)lbl[gid];
            else if (gid < 2 * Bn) v = (float)lbl[gid - Bn];
            else                   v = qps[gid - 2 * Bn];
            out_lab[gid] = v;
        }
        int j = gid - NL;
        if (j >= 0 && j < Qn) {
            unsigned rr = (unsigned)(j - pc);
            out_qps[j] = (rr < (unsigned)Bn) ? (float)lbl[rr] : qps[j];
        }
        if (gid == NL + Qn) out_ptr[0] = (float)((p + Bn) % Qn);
    }
}

// ---------------- host ----------------
extern "C" void kernel_launch(void* const* d_in, const int* in_sizes, int n_in,
                              void* d_out, int out_size, void* d_ws, size_t ws_size,
                              hipStream_t stream)
{
    const float* q     = (const float*)d_in[0];
    const float* kk    = (const float*)d_in[1];
    const float* cl    = (const float*)d_in[2];
    const float* plab  = (const float*)d_in[3];
    const float* proto = (const float*)d_in[4];
    const float* queue = (const float*)d_in[5];
    const float* qps   = (const float*)d_in[6];
    const int*   ptrp  = (const int*)d_in[7];

    float* out = (float*)d_out;
    // output layout (flat float offsets, return order)
    const long long O_CLU  = 4096000;     // cluster_out
    const long long O_FEAT = 8192000;     // cont_features
    const long long O_LAB  = 17629184;    // cont_labels
    const long long O_PROT = 17702912;    // new_prototypes
    const long long O_QUE  = 17830912;    // new_queue
    const long long O_QPS  = 26219520;    // new_queue_pseudo
    const long long O_PTR  = 26285056;    // new_ptr

    char* ws = (char*)d_ws;
    int*   lbl = (int*)(ws + 0);                           // [4096]
    __hip_bfloat16* qb = (__hip_bfloat16*)(ws + 1048576);  // [4096*128] bf16
    __hip_bfloat16* pb = (__hip_bfloat16*)(ws + 2097152);  // [1024*128] bf16 (padded)

    k_phase1<<<3072, 256, 0, stream>>>(cl, plab, q, proto, kk, queue, ptrp,
                                       out, lbl, qb, pb, out + O_FEAT, out + O_QUE);
    k_phase2<<<1301, 256, 0, stream>>>(qb, pb, proto, q, lbl, qps, ptrp,
                                       out + O_CLU, out + O_PROT,
                                       out + O_LAB, out + O_QPS, out + O_PTR);
}

// Round 11
// 47.292 us; speedup vs baseline: 1.2087x; 1.2087x over previous
//
#include <hip/hip_runtime.h>
#include <hip/hip_bf16.h>
#include <math.h>

// Problem sizes
#define Bn 4096
#define Dn 128
#define Cn 1000
#define Qn 65536
#define CPAD 1024   // proto rows padded (zeros) so fragment loads are in-bounds

typedef __attribute__((ext_vector_type(8))) short short8v;  // bf16x8 MFMA frag
typedef __attribute__((ext_vector_type(4))) short short4v;  // bf16x4 store
typedef __attribute__((ext_vector_type(4))) float f32x4;    // fp32x4 acc frag
typedef __attribute__((ext_vector_type(4))) float f4v;      // native float4

__device__ inline float waveAllMaxF(float v) {
    for (int o = 32; o; o >>= 1) v = fmaxf(v, __shfl_xor(v, o));
    return v;
}
__device__ inline float waveAllSumF(float v) {
    for (int o = 32; o; o >>= 1) v += __shfl_xor(v, o);
    return v;
}
__device__ inline float waveSumF(float v) {
    for (int o = 32; o; o >>= 1) v += __shfl_down(v, o);
    return v;
}
__device__ inline short f2bf(float x) {
    union { __hip_bfloat16 h; short s; } u;
    u.h = __float2bfloat16(x);
    return u.s;
}

// ================= K1: cls only =================
// 1024 blocks: 4 rows each, one wave per row (no barriers, no LDS)
// + bf16-convert fold (160 float4 per block, exact cover of qb+pb).
__global__ __launch_bounds__(256) void k_cls(
    const float* __restrict__ logits, const float* __restrict__ plabel,
    const float* __restrict__ q, const float* __restrict__ proto,
    float* __restrict__ out_cls, int* __restrict__ labels,
    __hip_bfloat16* __restrict__ qb, __hip_bfloat16* __restrict__ pb)
{
    int g = blockIdx.x, t = threadIdx.x;

    if (t < 160) {
        int idx4 = g * 160 + t;
        if (idx4 < 131072) {                      // q: 524288/4
            f4v v = *(const f4v*)(q + (long long)idx4 * 4);
            short4v o = {f2bf(v.x), f2bf(v.y), f2bf(v.z), f2bf(v.w)};
            *(short4v*)((short*)qb + (long long)idx4 * 4) = o;
        } else {
            int j4 = idx4 - 131072;               // proto: 32768 float4 slots (padded)
            short4v o = {0, 0, 0, 0};
            if (j4 < 32000) {
                f4v v = *(const f4v*)(proto + (long long)j4 * 4);
                o = (short4v){f2bf(v.x), f2bf(v.y), f2bf(v.z), f2bf(v.w)};
            }
            *(short4v*)((short*)pb + (long long)j4 * 4) = o;
        }
    }

    int lane = t & 63, wid = t >> 6;
    int row = g * 4 + wid;
    const float* x = logits + (long long)row * Cn;

    float vv[16];
    float mx = -INFINITY;
#pragma unroll
    for (int j = 0; j < 4; ++j) {
        int f4i = lane + j * 64;
        f4v v = (f4v){-INFINITY, -INFINITY, -INFINITY, -INFINITY};
        if (f4i < 250) v = *(const f4v*)(x + f4i * 4);
        vv[j * 4 + 0] = v.x; vv[j * 4 + 1] = v.y;
        vv[j * 4 + 2] = v.z; vv[j * 4 + 3] = v.w;
        mx = fmaxf(mx, fmaxf(fmaxf(v.x, v.y), fmaxf(v.z, v.w)));
    }
    mx = waveAllMaxF(mx);

    float ssum = 0.f;
#pragma unroll
    for (int u = 0; u < 16; ++u) {
        vv[u] = expf(vv[u] - mx);      // exp(-inf - mx) = 0 for masked slots
        ssum += vv[u];
    }
    ssum = waveAllSumF(ssum);
    float inv = 1.f / ssum;

    float bv = -INFINITY; int bi = Cn;
#pragma unroll
    for (int j = 0; j < 4; ++j) {
        int f4i = lane + j * 64;
        if (f4i < 250) {
            float o0 = vv[j * 4 + 0] * inv, o1 = vv[j * 4 + 1] * inv;
            float o2 = vv[j * 4 + 2] * inv, o3 = vv[j * 4 + 3] * inv;
            *((f4v*)(out_cls + (long long)row * Cn) + f4i) = (f4v){o0, o1, o2, o3};
            f4v p4 = *((const f4v*)(plabel + (long long)row * Cn) + f4i);
            float pr[4] = {o0 * p4.x, o1 * p4.y, o2 * p4.z, o3 * p4.w};
#pragma unroll
            for (int jj = 0; jj < 4; ++jj) {
                if (pr[jj] > bv) { bv = pr[jj]; bi = f4i * 4 + jj; }
            }
        }
    }
    for (int o = 32; o; o >>= 1) {
        float ov = __shfl_xor(bv, o);
        int   oi = __shfl_xor(bi, o);
        if (ov > bv || (ov == bv && oi < bi)) { bv = ov; bi = oi; }
    }
    if (lane == 0) labels[row] = bi;
}

// ================= K2: everything else =================
// 3349 blocks (compute roles FIRST so they hide under the copy stream):
//   bid <  256 : cluster GEMM + row softmax (16 rows/block, bf16 qb/pb)
//   bid <  756 : prototype EMA + L2 norm (round-9 LDS-staged, 2 classes/block)
//   bid < 1301 : cont_labels / new_queue_pseudo / new_ptr tail (545 blocks)
//   else       : copy (2048 blocks): cont_features + new_queue streaming
__global__ __launch_bounds__(256) void k_rest(
    const __hip_bfloat16* __restrict__ qb, const __hip_bfloat16* __restrict__ pb,
    const float* __restrict__ proto, const float* __restrict__ q,
    const float* __restrict__ kk, const float* __restrict__ queue,
    const int* __restrict__ lbl, const float* __restrict__ qps,
    const int* __restrict__ ptrp,
    float* __restrict__ outC, float* __restrict__ outp,
    float* __restrict__ out_lab, float* __restrict__ out_qps,
    float* __restrict__ out_ptr,
    float* __restrict__ out_feat, float* __restrict__ out_queue)
{
    __shared__ __align__(16) char smem[32800];
    int bid = blockIdx.x, t = threadIdx.x;

    if (bid >= 1301) {
        // ---- copy block (2048 total) ----
        int cidx = bid - 1301;
        int p = *ptrp;
        int pc = p < 0 ? 0 : (p > Qn - Bn ? Qn - Bn : p);   // dynamic_update_slice clamp
        const long long QD = (long long)Bn * Dn;                  // 524288
        const long long n4 = (2 * QD + (long long)Qn * Dn) / 4;   // 2359296
        const long long stride = 2048LL * 256;
        for (long long i = (long long)cidx * 256 + t; i < n4; i += stride) {
            long long off = i * 4;
            if (off < QD) {
                *(f4v*)(out_feat + off) = *(const f4v*)(q + off);
            } else if (off < 2 * QD) {
                *(f4v*)(out_feat + off) = *(const f4v*)(kk + off - QD);
            } else {
                long long qoff = off - 2 * QD;
                f4v v = *(const f4v*)(queue + qoff);
                *(f4v*)(out_feat + off) = v;
                int row = (int)(qoff >> 7);
                int col = (int)(qoff & 127);
                unsigned rr = (unsigned)(row - pc);
                if (rr < (unsigned)Bn) v = *(const f4v*)(kk + (long long)rr * Dn + col);
                *(f4v*)(out_queue + qoff) = v;
            }
        }
        return;
    }

    if (bid < 256) {
        // ---- GEMM + softmax ----
        float (*red)[4] = (float (*)[4])smem;   // [16][4]
        int lane = t & 63, w = t >> 6;
        int la = lane & 15, lk = lane >> 4;
        int row0 = bid * 16;

        f32x4 acc[16];
#pragma unroll
        for (int j = 0; j < 16; ++j) acc[j] = (f32x4){0.f, 0.f, 0.f, 0.f};

        const short* A = (const short*)qb + (long long)(row0 + la) * Dn;
        const short* Bp = (const short*)pb;
#pragma unroll
        for (int kc = 0; kc < Dn; kc += 32) {
            short8v a = *(const short8v*)(A + kc + lk * 8);
#pragma unroll
            for (int j = 0; j < 16; ++j) {
                int prow = w * 256 + j * 16 + la;
                short8v b = *(const short8v*)(Bp + (long long)prow * Dn + kc + lk * 8);
                acc[j] = __builtin_amdgcn_mfma_f32_16x16x32_bf16(a, b, acc[j], 0, 0, 0);
            }
        }

        float m[4];
#pragma unroll
        for (int rg = 0; rg < 4; ++rg) {
            float v = -INFINITY;
#pragma unroll
            for (int j = 0; j < 16; ++j) {
                int col = w * 256 + j * 16 + la;
                if (col < Cn) v = fmaxf(v, acc[j][rg]);
            }
#pragma unroll
            for (int o = 1; o < 16; o <<= 1) v = fmaxf(v, __shfl_xor(v, o));
            m[rg] = v;
        }
        if (la == 0) {
#pragma unroll
            for (int rg = 0; rg < 4; ++rg) red[lk * 4 + rg][w] = m[rg];
        }
        __syncthreads();
#pragma unroll
        for (int rg = 0; rg < 4; ++rg) {
            int r = lk * 4 + rg;
            m[rg] = fmaxf(fmaxf(red[r][0], red[r][1]), fmaxf(red[r][2], red[r][3]));
        }
        __syncthreads();

        float s[4];
#pragma unroll
        for (int rg = 0; rg < 4; ++rg) {
            float v = 0.f;
#pragma unroll
            for (int j = 0; j < 16; ++j) {
                int col = w * 256 + j * 16 + la;
                float e = (col < Cn) ? expf(acc[j][rg] - m[rg]) : 0.f;
                acc[j][rg] = e;
                v += e;
            }
#pragma unroll
            for (int o = 1; o < 16; o <<= 1) v += __shfl_xor(v, o);
            s[rg] = v;
        }
        if (la == 0) {
#pragma unroll
            for (int rg = 0; rg < 4; ++rg) red[lk * 4 + rg][w] = s[rg];
        }
        __syncthreads();
#pragma unroll
        for (int rg = 0; rg < 4; ++rg) {
            int r = lk * 4 + rg;
            s[rg] = 1.f / (red[r][0] + red[r][1] + red[r][2] + red[r][3]);
        }

#pragma unroll
        for (int j = 0; j < 16; ++j) {
            int col = w * 256 + j * 16 + la;
            if (col < Cn) {
                int rowb = row0 + lk * 4;
#pragma unroll
                for (int rg = 0; rg < 4; ++rg)
                    outC[(long long)(rowb + rg) * Cn + col] = acc[j][rg] * s[rg];
            }
        }
    } else if (bid < 756) {
        // ---- prototype EMA + L2 norm, 2 classes per block (round-9 form) ----
        int* sl = (int*)smem;                                    // [4096]
        unsigned short* list0 = (unsigned short*)(smem + 16384); // [4096]
        unsigned short* list1 = list0 + 4096;                    // [4096]
        int* nm = (int*)(smem + 32768);                          // [2]
        float* shh = (float*)(smem + 32776);                     // [4]

        int h = t >> 7, tt = t & 127;
        int c = (bid - 256) * 2 + h;                             // < 1000 always

#pragma unroll
        for (int u = 0; u < 4; ++u) {
            int base = (u * 256 + t) * 4;
            *(int4*)(sl + base) = *(const int4*)(lbl + base);
        }
        if (t == 0)   nm[0] = 0;
        if (t == 128) nm[1] = 0;
        __syncthreads();

        int wv = t >> 6;
        if ((wv & 1) == 0) {            // waves 0 and 2 scan for their half's class
            int hh = wv >> 1;
            int ln = t & 63;
            int cc = (bid - 256) * 2 + hh;
            unsigned short* lst = hh ? list1 : list0;
            int n = 0;
            for (int jj = 0; jj < Bn / 64; ++jj) {
                unsigned long long mask = __ballot(sl[jj * 64 + ln] == cc);
                if (ln == 0) {
                    while (mask) {
                        int b = __builtin_ctzll(mask);
                        lst[n++] = (unsigned short)(jj * 64 + b);
                        mask &= mask - 1;
                    }
                }
            }
            if (ln == 0) nm[hh] = n;
        }
        __syncthreads();

        int n = nm[h];
        unsigned short* lst = h ? list1 : list0;
        float acc = proto[(long long)c * Dn + tt];
        for (int mi = 0; mi < n; ++mi)
            acc = 0.99f * acc + 0.01f * q[(long long)lst[mi] * Dn + tt];

        float ss = waveSumF(acc * acc);
        if ((t & 63) == 0) shh[t >> 6] = ss;
        __syncthreads();
        float nn = sqrtf(shh[h * 2] + shh[h * 2 + 1]);
        outp[(long long)c * Dn + tt] = acc / fmaxf(nn, 1e-12f);
    } else {
        // ---- labels / queue_pseudo / ptr tail (545 blocks) ----
        int gid = (bid - 756) * 256 + t;
        const int NL = 2 * Bn + Qn;   // 73728
        int p = *ptrp;
        int pc = p < 0 ? 0 : (p > Qn - Bn ? Qn - Bn : p);
        if (gid < NL) {
            float v;
            if (gid < Bn)          v = (float)lbl[gid];
            else if (gid < 2 * Bn) v = (float)lbl[gid - Bn];
            else                   v = qps[gid - 2 * Bn];
            out_lab[gid] = v;
        }
        int j = gid - NL;
        if (j >= 0 && j < Qn) {
            unsigned rr = (unsigned)(j - pc);
            out_qps[j] = (rr < (unsigned)Bn) ? (float)lbl[rr] : qps[j];
        }
        if (gid == NL + Qn) out_ptr[0] = (float)((p + Bn) % Qn);
    }
}

// ---------------- host ----------------
extern "C" void kernel_launch(void* const* d_in, const int* in_sizes, int n_in,
                              void* d_out, int out_size, void* d_ws, size_t ws_size,
                              hipStream_t stream)
{
    const float* q     = (const float*)d_in[0];
    const float* kk    = (const float*)d_in[1];
    const float* cl    = (const float*)d_in[2];
    const float* plab  = (const float*)d_in[3];
    const float* proto = (const float*)d_in[4];
    const float* queue = (const float*)d_in[5];
    const float* qps   = (const float*)d_in[6];
    const int*   ptrp  = (const int*)d_in[7];

    float* out = (float*)d_out;
    // output layout (flat float offsets, return order)
    const long long O_CLU  = 4096000;     // cluster_out
    const long long O_FEAT = 8192000;     // cont_features
    const long long O_LAB  = 17629184;    // cont_labels
    const long long O_PROT = 17702912;    // new_prototypes
    const long long O_QUE  = 17830912;    // new_queue
    const long long O_QPS  = 26219520;    // new_queue_pseudo
    const long long O_PTR  = 26285056;    // new_ptr

    char* ws = (char*)d_ws;
    int*   lbl = (int*)(ws + 0);                           // [4096]
    __hip_bfloat16* qb = (__hip_bfloat16*)(ws + 1048576);  // [4096*128] bf16
    __hip_bfloat16* pb = (__hip_bfloat16*)(ws + 2097152);  // [1024*128] bf16 (padded)

    k_cls<<<1024, 256, 0, stream>>>(cl, plab, q, proto, out, lbl, qb, pb);
    k_rest<<<3349, 256, 0, stream>>>(qb, pb, proto, q, kk, queue, lbl, qps, ptrp,
                                     out + O_CLU, out + O_PROT,
                                     out + O_LAB, out + O_QPS, out + O_PTR,
                                     out + O_FEAT, out + O_QUE);
}